// Round 8
// baseline (249.509 us; speedup 1.0000x reference)
//
#include <hip/hip_runtime.h>
#include <hip/hip_bf16.h>

#define M_TOTAL 65536
#define N_TOTAL 1024
#define K_TOTAL 1024

typedef __attribute__((ext_vector_type(8))) short short8;
typedef __attribute__((ext_vector_type(4))) float f32x4;
typedef __attribute__((ext_vector_type(4))) int   i32x4;

typedef __attribute__((address_space(3))) void lds_vp;
typedef const __attribute__((address_space(1))) void glb_vp;

#define BAR()    asm volatile("s_barrier" ::: "memory")
#define WAITV8() asm volatile("s_waitcnt vmcnt(8)" ::: "memory")
#define WAITV0() asm volatile("s_waitcnt vmcnt(0)" ::: "memory")
#define WAITL0() asm volatile("s_waitcnt lgkmcnt(0)" ::: "memory")

#define MAGIC 12582912.0f   // 1.5*2^23: low byte of (r+MAGIC) = (int8)rint(r)

static __device__ __forceinline__ unsigned fbits(float f) {
    union { float f; unsigned u; } c; c.f = f; return c.u;
}
// pack low bytes of 4 magic-biased floats into one dword (verified r6/r7)
static __device__ __forceinline__ unsigned pk4(float g0, float g1, float g2, float g3) {
    unsigned p01 = __builtin_amdgcn_perm(fbits(g1), fbits(g0), 0x0C0C0400u);
    unsigned p23 = __builtin_amdgcn_perm(fbits(g3), fbits(g2), 0x04000C0Cu);
    return p01 | p23;
}
// non-contracted multiply: keep rint semantics of (v*inv)+MAGIC exact (r7 ok)
static __device__ __forceinline__ float mulnc(float a, float b) {
    float t = a * b; asm volatile("" : "+v"(t)); return t;
}
// pack hi16 halves (bf16 of integer-valued f32) — fallback path
static __device__ __forceinline__ unsigned pkhi(float lo, float hi) {
    return __builtin_amdgcn_perm(fbits(hi), fbits(lo), 0x07060302u);
}

// ===================== FAST PATH (i8, LDS-free GEMM) ========================
// Tile layout (UNswizzled, linear): [blk][kt(16)][128 rows][64 K-bytes] i8.

// W: [1024][1024] f32 ints -> Wb [bnb(8)][kt][128][64]; also writes s_a tail.
__global__ void wconv8(const float* __restrict__ Wq, const float* __restrict__ SXp,
                       const float* __restrict__ SW, char* __restrict__ Wb,
                       float* __restrict__ Out) {
    const int n = blockIdx.x, c4 = threadIdx.x * 4;   // 1024 x 256
    float4 v = *(const float4*)(Wq + (size_t)n * K_TOTAL + c4);
    unsigned dw = pk4(v.x + MAGIC, v.y + MAGIC, v.z + MAGIC, v.w + MAGIC);
    const int bnb = n >> 7, row = n & 127, kt = c4 >> 6, c = c4 & 63;
    *(unsigned*)(Wb + (size_t)(bnb * 16 + kt) * 8192 + row * 64 + c) = dw;
    if (threadIdx.x == 0)
        Out[(size_t)M_TOTAL * N_TOTAL + n] = SW[n] * SXp[0];
}

// X: [65536][1024] f32 -> Xb [bmb(512)][kt][128][64] i8 (quantize, linear)
__global__ __launch_bounds__(256)
void xconv8(const float* __restrict__ X, const float* __restrict__ SXp,
            char* __restrict__ Xb) {
    const float inv_sx = 1.0f / SXp[0];
    const unsigned gid = blockIdx.x * 256 + threadIdx.x;  // 4,194,304 total
    const int slot = gid & 3;
    const int row  = (gid >> 2) & 127;
    const int kt   = (gid >> 9) & 15;
    const int bmb  = gid >> 13;
    const float* src = X + (size_t)(bmb * 128 + row) * K_TOTAL + kt * 64 + slot * 16;
    unsigned u[4];
    #pragma unroll
    for (int q = 0; q < 4; ++q) {
        float4 v = *(const float4*)(src + q * 4);
        u[q] = pk4(mulnc(v.x, inv_sx) + MAGIC, mulnc(v.y, inv_sx) + MAGIC,
                   mulnc(v.z, inv_sx) + MAGIC, mulnc(v.w, inv_sx) + MAGIC);
    }
    *(uint4*)(Xb + (size_t)(bmb * 16 + kt) * 8192 + row * 64 + slot * 16) =
        make_uint4(u[0], u[1], u[2], u[3]);
}

// GEMM: 128x128 tile, 4 waves, NO LDS / NO barriers — fragments loaded
// straight from L2-resident prepacked tiles into VGPRs.
__global__ __launch_bounds__(256, 3)
void qgemm8(const char* __restrict__ Xb, const float* __restrict__ SXp,
            const char* __restrict__ Wb, const float* __restrict__ SW,
            const float* __restrict__ Bq, float* __restrict__ Out)
{
    const int d = blockIdx.x;
    const int g = (d & 7) * 512 + (d >> 3);    // XCD-bijective (4096 % 8 == 0)
    const int bn_idx = g & 7, bm_idx = g >> 3;

    const int lane = threadIdx.x & 63, w = threadIdx.x >> 6;
    const int wm = (w >> 1) << 6, wn = (w & 1) << 6;
    const int fr = lane & 15, fg = lane >> 4;

    // per-lane fragment base: row (wq + i*16 + fr), K-bytes fg*16
    const char* ap = Xb + (size_t)bm_idx * 131072 + (wm + fr) * 64 + fg * 16;
    const char* bp = Wb + (size_t)bn_idx * 131072 + (wn + fr) * 64 + fg * 16;

    const float sx = SXp[0], inv_sx = 1.0f / sx;

    i32x4 acc[4][4] = {};
    i32x4 a0[4], b0[4], a1[4], b1[4];         // two named sets (rule #20)

    auto LD = [&](const char* p, i32x4* f) {
        f[0] = *(const i32x4*)(p);
        f[1] = *(const i32x4*)(p + 1024);     // imm offsets (i*1024 < 4096)
        f[2] = *(const i32x4*)(p + 2048);
        f[3] = *(const i32x4*)(p + 3072);
    };
    auto MM = [&](const i32x4* a, const i32x4* b) {
        #pragma unroll
        for (int i = 0; i < 4; ++i)
            #pragma unroll
            for (int j = 0; j < 4; ++j)
                acc[i][j] = __builtin_amdgcn_mfma_i32_16x16x64_i8(
                    a[i], b[j], acc[i][j], 0, 0, 0);
    };

    LD(ap, a0); LD(bp, b0);
    #pragma unroll
    for (int t = 0; t < 16; t += 2) {
        if (t + 1 < 16) { LD(ap + (t + 1) * 8192, a1); LD(bp + (t + 1) * 8192, b1); }
        MM(a0, b0);
        if (t + 2 < 16) { LD(ap + (t + 2) * 8192, a0); LD(bp + (t + 2) * 8192, b0); }
        MM(a1, b1);
    }

    // epilogue: (acc_i32 + rint(b/s_x)) * (s_w*s_x); exact (|acc|+|b32| < 2^24)
    // C/D layout: col = lane&15, row = (lane>>4)*4 + r. Nontemporal stores keep
    // the 268 MB stream out of L2 so Xb/Wb stay resident.
    const int bm0 = bm_idx * 128, bn0 = bn_idx * 128;
    #pragma unroll
    for (int n = 0; n < 4; ++n) {
        const int col = bn0 + wn + n * 16 + fr;
        const float sa  = SW[col] * sx;
        const float b32 = rintf(Bq[col] * inv_sx);
        #pragma unroll
        for (int m = 0; m < 4; ++m) {
            const size_t r0 = (size_t)(bm0 + wm + m * 16 + fg * 4) * N_TOTAL + col;
            #pragma unroll
            for (int r = 0; r < 4; ++r)
                __builtin_nontemporal_store(((float)acc[m][n][r] + b32) * sa,
                                            &Out[r0 + (size_t)r * N_TOTAL]);
        }
    }
}

// ===================== FALLBACK (r5 bf16 kernel, 221us) ======================
__global__ void wconv_bf(const float* __restrict__ Wq, ushort* __restrict__ Wb) {
    const int n = blockIdx.x, c4 = threadIdx.x * 4;
    float4 v = *(const float4*)(Wq + (size_t)n * K_TOTAL + c4);
    const int bnb = n >> 8, row = n & 255, kt = c4 >> 6, c = c4 & 63;
    const int cs = c ^ ((row & 7) << 3);
    ushort* dst = Wb + ((size_t)(bnb * 16 + kt) * 16384 + row * 64 + cs);
    *(uint2*)dst = make_uint2(pkhi(v.x, v.y), pkhi(v.z, v.w));
}

__global__ __launch_bounds__(512, 2)
void qgemm_bf(const float* __restrict__ X, const float* __restrict__ SXp,
              const ushort* __restrict__ Wb, const float* __restrict__ SW,
              const float* __restrict__ Bq, float* __restrict__ Out)
{
    __shared__ uint4 smem4[8192];
    char* const smem = (char*)smem4;
    const int tid = threadIdx.x;
    const int d = blockIdx.x;
    const int g = (d & 7) * 128 + (d >> 3);
    const int bn_idx = g & 3, bm_idx = g >> 2;
    const int bm0 = bm_idx * 256, bn0 = bn_idx * 256;
    const float sx = SXp[0], inv_sx = 1.0f / sx;
    const int ar = tid >> 2, ac = (tid & 3) << 4;
    const float* xg = X + (size_t)(bm0 + ar) * K_TOTAL + ac;
    const int awslot = (tid & 3) << 1;
    const int awsw0 = ((awslot    ) ^ (ar & 7)) << 4;
    const int awsw1 = ((awslot + 1) ^ (ar & 7)) << 4;
    const int lane = tid & 63, w = tid >> 6;
    const int wm = (w >> 2) << 7, wn = (w & 3) << 6;
    const int fr = lane & 15, fg = lane >> 4;
    const int s0 = ((fg    ) ^ (fr & 7)) << 4;
    const int s1 = ((fg + 4) ^ (fr & 7)) << 4;
    const int arow = (wm + fr) * 128, brow = (wn + fr) * 128;
    const char* wsrc = (const char*)Wb + (size_t)bn_idx * 16 * 32768
                     + w * 4096 + lane * 16;
    f32x4 acc[8][4] = {};
    float4 xh0[4], xh1[4];
    short8 af[4], bf[4];
    auto issueA = [&](int kt, int h, float4* dst) {
        const float4* p = (const float4*)(xg + (size_t)h * 128 * K_TOTAL + kt * 64);
        dst[0] = p[0]; dst[1] = p[1]; dst[2] = p[2]; dst[3] = p[3];
    };
    auto packA = [&](int buf, int h, const float4* v) {
        unsigned u[8];
        #pragma unroll
        for (int q = 0; q < 4; ++q) {
            u[2*q+0] = pkhi(rintf(v[q].x * inv_sx), rintf(v[q].y * inv_sx));
            u[2*q+1] = pkhi(rintf(v[q].z * inv_sx), rintf(v[q].w * inv_sx));
        }
        char* base = smem + buf * 32768 + (h * 128 + ar) * 128;
        *(uint4*)(base + awsw0) = make_uint4(u[0], u[1], u[2], u[3]);
        *(uint4*)(base + awsw1) = make_uint4(u[4], u[5], u[6], u[7]);
    };
    auto gldsB = [&](int kt, int buf) {
        const char* src = wsrc + (size_t)kt * 32768;
        char* dst = smem + 65536 + buf * 32768 + w * 4096;
        __builtin_amdgcn_global_load_lds((glb_vp*)(src +    0), (lds_vp*)(dst +    0), 16, 0, 0);
        __builtin_amdgcn_global_load_lds((glb_vp*)(src + 1024), (lds_vp*)(dst + 1024), 16, 0, 0);
        __builtin_amdgcn_global_load_lds((glb_vp*)(src + 2048), (lds_vp*)(dst + 2048), 16, 0, 0);
        __builtin_amdgcn_global_load_lds((glb_vp*)(src + 3072), (lds_vp*)(dst + 3072), 16, 0, 0);
    };
    auto readA = [&](int buf, int mh, int sk) {
        const char* base = smem + buf * 32768 + arow;
        #pragma unroll
        for (int i = 0; i < 4; ++i)
            af[i] = *(const short8*)(base + (mh * 64 + i * 16) * 128 + sk);
    };
    auto readB = [&](int buf, int sk) {
        const char* base = smem + 65536 + buf * 32768 + brow;
        #pragma unroll
        for (int j = 0; j < 4; ++j)
            bf[j] = *(const short8*)(base + (j * 16) * 128 + sk);
    };
    auto mfma16 = [&](int mh) {
        __builtin_amdgcn_s_setprio(1);
        #pragma unroll
        for (int i = 0; i < 4; ++i)
            #pragma unroll
            for (int j = 0; j < 4; ++j)
                acc[mh*4+i][j] = __builtin_amdgcn_mfma_f32_16x16x32_bf16(
                    af[i], bf[j], acc[mh*4+i][j], 0, 0, 0);
        __builtin_amdgcn_s_setprio(0);
    };
    issueA(0, 0, xh0); issueA(0, 1, xh1);
    gldsB(0, 0);
    packA(0, 0, xh0); packA(0, 1, xh1);
    issueA(1, 0, xh0); issueA(1, 1, xh1);
    WAITV8(); WAITL0(); BAR();
    for (int t = 0; t < 16; ++t) {
        const int cur = t & 1, nxt = cur ^ 1;
        const bool pf  = (t + 1 < 16);
        const bool pf2 = (t + 2 < 16);
        if (pf) gldsB(t + 1, nxt);
        readA(cur, 0, s0); readB(cur, s0);
        BAR(); mfma16(0); BAR();
        readA(cur, 1, s0);
        BAR(); mfma16(1); BAR();
        if (pf)  packA(nxt, 0, xh0);
        if (pf2) issueA(t + 2, 0, xh0);
        readA(cur, 0, s1); readB(cur, s1);
        BAR(); mfma16(0); BAR();
        if (pf)  packA(nxt, 1, xh1);
        if (pf2) issueA(t + 2, 1, xh1);
        readA(cur, 1, s1);
        BAR(); mfma16(1);
        if (pf) {
            if (pf2) WAITV8(); else WAITV0();
            WAITL0(); BAR();
        }
    }
    #pragma unroll
    for (int n = 0; n < 4; ++n) {
        const int col = bn0 + wn + n * 16 + fr;
        const float sa  = SW[col] * sx;
        const float b32 = rintf(Bq[col] * inv_sx);
        #pragma unroll
        for (int m = 0; m < 8; ++m) {
            const size_t r0 = (size_t)(bm0 + wm + m * 16 + fg * 4) * N_TOTAL + col;
            #pragma unroll
            for (int r = 0; r < 4; ++r)
                Out[r0 + (size_t)r * N_TOTAL] = (acc[m][n][r] + b32) * sa;
        }
    }
}

__global__ void sa_tail(const float* __restrict__ SW, const float* __restrict__ SXp,
                        float* __restrict__ Out)
{
    int o = blockIdx.x * blockDim.x + threadIdx.x;
    if (o < N_TOTAL) Out[(size_t)M_TOTAL * N_TOTAL + o] = SW[o] * SXp[0];
}

extern "C" void kernel_launch(void* const* d_in, const int* in_sizes, int n_in,
                              void* d_out, int out_size, void* d_ws, size_t ws_size,
                              hipStream_t stream)
{
    const float* x  = (const float*)d_in[0];
    const float* sx = (const float*)d_in[1];
    const float* wq = (const float*)d_in[2];
    const float* sw = (const float*)d_in[3];
    const float* bq = (const float*)d_in[4];
    float* out = (float*)d_out;

    const size_t W_BYTES = 1u << 20;          // Wb: 1 MiB
    const size_t X_BYTES = (size_t)64 << 20;  // Xb: 64 MiB

    if (ws_size >= W_BYTES + X_BYTES) {
        char* wbuf = (char*)d_ws;
        char* xbuf = (char*)d_ws + W_BYTES;
        wconv8<<<1024, 256, 0, stream>>>(wq, sx, sw, wbuf, out);
        xconv8<<<16384, 256, 0, stream>>>(x, sx, xbuf);
        qgemm8<<<4096, 256, 0, stream>>>(xbuf, sx, wbuf, sw, bq, out);
    } else {
        ushort* wbuf = (ushort*)d_ws;         // 2 MiB (r5 path)
        wconv_bf<<<1024, 256, 0, stream>>>(wq, wbuf);
        qgemm_bf<<<1024, 512, 0, stream>>>(x, sx, wbuf, sw, bq, out);
        sa_tail<<<4, 256, 0, stream>>>(sw, sx, out);
    }
}

// Round 9
// 239.307 us; speedup vs baseline: 1.0426x; 1.0426x over previous
//
#include <hip/hip_runtime.h>
#include <hip/hip_bf16.h>

#define M_TOTAL 65536
#define N_TOTAL 1024
#define K_TOTAL 1024

typedef __attribute__((ext_vector_type(8))) short short8;
typedef __attribute__((ext_vector_type(4))) float f32x4;
typedef __attribute__((ext_vector_type(4))) int   i32x4;

typedef __attribute__((address_space(3))) void lds_vp;
typedef const __attribute__((address_space(1))) void glb_vp;

#define BAR()    asm volatile("s_barrier" ::: "memory")
#define WAITV8() asm volatile("s_waitcnt vmcnt(8)" ::: "memory")
#define WAITV4() asm volatile("s_waitcnt vmcnt(4)" ::: "memory")
#define WAITV0() asm volatile("s_waitcnt vmcnt(0)" ::: "memory")
#define WAITL0() asm volatile("s_waitcnt lgkmcnt(0)" ::: "memory")

#define MAGIC 12582912.0f   // 1.5*2^23: low byte of (r+MAGIC) = (int8)rint(r)

static __device__ __forceinline__ unsigned fbits(float f) {
    union { float f; unsigned u; } c; c.f = f; return c.u;
}
// pack low bytes of 4 magic-biased floats into one dword (verified r6/r7)
static __device__ __forceinline__ unsigned pk4(float g0, float g1, float g2, float g3) {
    unsigned p01 = __builtin_amdgcn_perm(fbits(g1), fbits(g0), 0x0C0C0400u);
    unsigned p23 = __builtin_amdgcn_perm(fbits(g3), fbits(g2), 0x04000C0Cu);
    return p01 | p23;
}
// non-contracted multiply: keep rint semantics of (v*inv)+MAGIC exact
static __device__ __forceinline__ float mulnc(float a, float b) {
    float t = a * b; asm volatile("" : "+v"(t)); return t;
}
// pack hi16 halves (bf16 of integer-valued f32) — fallback path
static __device__ __forceinline__ unsigned pkhi(float lo, float hi) {
    return __builtin_amdgcn_perm(fbits(hi), fbits(lo), 0x07060302u);
}

// ===================== FAST PATH (i8, glds 3-buffer pipeline) ================
// Tile layout: [blk][kt(16)][128 rows][64 K-bytes] i8, PRE-SWIZZLED: logical
// 16B-slot s of row r stored at slot s ^ ((r>>1)&3)  (linear glds fill +
// swizzled ds_read -> 2-way max bank aliasing, proven 0 conflicts in r7).

// W: [1024][1024] f32 ints -> Wb [bnb(8)][kt][128][64]; also writes s_a tail.
__global__ void wconv8(const float* __restrict__ Wq, const float* __restrict__ SXp,
                       const float* __restrict__ SW, char* __restrict__ Wb,
                       float* __restrict__ Out) {
    const int n = blockIdx.x, c4 = threadIdx.x * 4;   // 1024 x 256
    float4 v = *(const float4*)(Wq + (size_t)n * K_TOTAL + c4);
    unsigned dw = pk4(v.x + MAGIC, v.y + MAGIC, v.z + MAGIC, v.w + MAGIC);
    const int bnb = n >> 7, row = n & 127, kt = c4 >> 6, c = c4 & 63;
    const int cs = (((c >> 4) ^ ((row >> 1) & 3)) << 4) + (c & 15);
    *(unsigned*)(Wb + (size_t)(bnb * 16 + kt) * 8192 + row * 64 + cs) = dw;
    if (threadIdx.x == 0)
        Out[(size_t)M_TOTAL * N_TOTAL + n] = SW[n] * SXp[0];
}

// X: [65536][1024] f32 -> Xb [bmb(512)][kt][128][64] i8 (quantize + swizzle)
__global__ __launch_bounds__(256)
void xconv8(const float* __restrict__ X, const float* __restrict__ SXp,
            char* __restrict__ Xb) {
    const float inv_sx = 1.0f / SXp[0];
    const unsigned gid = blockIdx.x * 256 + threadIdx.x;  // 4,194,304 total
    const int slot = gid & 3;
    const int row  = (gid >> 2) & 127;
    const int kt   = (gid >> 9) & 15;
    const int bmb  = gid >> 13;
    const float* src = X + (size_t)(bmb * 128 + row) * K_TOTAL + kt * 64 + slot * 16;
    unsigned u[4];
    #pragma unroll
    for (int q = 0; q < 4; ++q) {
        float4 v = *(const float4*)(src + q * 4);
        u[q] = pk4(mulnc(v.x, inv_sx) + MAGIC, mulnc(v.y, inv_sx) + MAGIC,
                   mulnc(v.z, inv_sx) + MAGIC, mulnc(v.w, inv_sx) + MAGIC);
    }
    const int p = slot ^ ((row >> 1) & 3);
    *(uint4*)(Xb + (size_t)(bmb * 16 + kt) * 8192 + row * 64 + p * 16) =
        make_uint4(u[0], u[1], u[2], u[3]);
}

// GEMM: 128x128 tile, 4 waves, glds both operands, 3-buffer counted pipeline.
__global__ __launch_bounds__(256, 3)
void qgemm8(const char* __restrict__ Xb, const float* __restrict__ SXp,
            const char* __restrict__ Wb, const float* __restrict__ SW,
            const float* __restrict__ Bq, float* __restrict__ Out)
{
    __shared__ uint4 smem4[3072];          // 48 KiB: A 3x8K @0, B 3x8K @24576
    char* const smem = (char*)smem4;

    const int d = blockIdx.x;
    const int g = (d & 7) * 512 + (d >> 3);    // XCD-bijective (4096 % 8 == 0)
    const int bn_idx = g & 7, bm_idx = g >> 3;

    const int lane = threadIdx.x & 63, w = threadIdx.x >> 6;
    const int wm = (w >> 1) << 6, wn = (w & 1) << 6;
    const int fr = lane & 15, fg = lane >> 4;
    const int sslot = ((fg ^ ((fr >> 1) & 3)) << 4);
    const int arow = (wm + fr) * 64;
    const int brow = (wn + fr) * 64;

    // glds sources: wave w covers bytes [w*2048, w*2048+2048) of each 8KB tile
    const char* asrc = Xb + (size_t)bm_idx * 131072 + w * 2048 + lane * 16;
    const char* bsrc = Wb + (size_t)bn_idx * 131072 + w * 2048 + lane * 16;

    const float sx = SXp[0], inv_sx = 1.0f / sx;

    i32x4 acc[4][4] = {};
    i32x4 af[4], bf[4];

    auto glds = [&](int kt, int buf) {
        const char* sa = asrc + (size_t)kt * 8192;
        const char* sb = bsrc + (size_t)kt * 8192;
        char* da = smem +         buf * 8192 + w * 2048;
        char* db = smem + 24576 + buf * 8192 + w * 2048;
        __builtin_amdgcn_global_load_lds((glb_vp*)(sa +    0), (lds_vp*)(da +    0), 16, 0, 0);
        __builtin_amdgcn_global_load_lds((glb_vp*)(sa + 1024), (lds_vp*)(da + 1024), 16, 0, 0);
        __builtin_amdgcn_global_load_lds((glb_vp*)(sb +    0), (lds_vp*)(db +    0), 16, 0, 0);
        __builtin_amdgcn_global_load_lds((glb_vp*)(sb + 1024), (lds_vp*)(db + 1024), 16, 0, 0);
    };

    // prologue: 2 tiles in flight
    glds(0, 0);
    glds(1, 1);

    #pragma unroll
    for (int t = 0; t < 16; ++t) {
        const int buf = t % 3;
        // retire glds(t) ONLY; glds(t+1) stays in flight across the barrier
        if (t < 15) WAITV4(); else WAITV0();
        BAR();                              // all waves' glds(t) visible
        // safe here: every wave is past its tile t-1 ds_reads (consumed by
        // MFMA(t-1) before BAR), so overwriting buf (t+2)%3 == (t-1)%3 is WAR-clean
        if (t + 2 < 16) glds(t + 2, (t + 2) % 3);
        {
            const char* ab = smem +         buf * 8192 + arow + sslot;
            const char* bb = smem + 24576 + buf * 8192 + brow + sslot;
            #pragma unroll
            for (int i = 0; i < 4; ++i)
                af[i] = *(const i32x4*)(ab + (i * 16) * 64);
            #pragma unroll
            for (int j = 0; j < 4; ++j)
                bf[j] = *(const i32x4*)(bb + (j * 16) * 64);
        }
        __builtin_amdgcn_s_setprio(1);
        #pragma unroll
        for (int i = 0; i < 4; ++i)
            #pragma unroll
            for (int j = 0; j < 4; ++j)
                acc[i][j] = __builtin_amdgcn_mfma_i32_16x16x64_i8(
                    af[i], bf[j], acc[i][j], 0, 0, 0);
        __builtin_amdgcn_s_setprio(0);
    }

    // epilogue: (acc_i32 + rint(b/s_x)) * (s_w*s_x); exact (|acc|+|b32| < 2^24)
    // C/D layout: col = lane&15, row = (lane>>4)*4 + r
    const int bm0 = bm_idx * 128, bn0 = bn_idx * 128;
    #pragma unroll
    for (int n = 0; n < 4; ++n) {
        const int col = bn0 + wn + n * 16 + fr;
        const float sa  = SW[col] * sx;
        const float b32 = rintf(Bq[col] * inv_sx);
        #pragma unroll
        for (int m = 0; m < 4; ++m) {
            const size_t r0 = (size_t)(bm0 + wm + m * 16 + fg * 4) * N_TOTAL + col;
            #pragma unroll
            for (int r = 0; r < 4; ++r)
                Out[r0 + (size_t)r * N_TOTAL] = ((float)acc[m][n][r] + b32) * sa;
        }
    }
}

// ===================== FALLBACK (r5 bf16 kernel, 221us) ======================
__global__ void wconv_bf(const float* __restrict__ Wq, ushort* __restrict__ Wb) {
    const int n = blockIdx.x, c4 = threadIdx.x * 4;
    float4 v = *(const float4*)(Wq + (size_t)n * K_TOTAL + c4);
    const int bnb = n >> 8, row = n & 255, kt = c4 >> 6, c = c4 & 63;
    const int cs = c ^ ((row & 7) << 3);
    ushort* dst = Wb + ((size_t)(bnb * 16 + kt) * 16384 + row * 64 + cs);
    *(uint2*)dst = make_uint2(pkhi(v.x, v.y), pkhi(v.z, v.w));
}

__global__ __launch_bounds__(512, 2)
void qgemm_bf(const float* __restrict__ X, const float* __restrict__ SXp,
              const ushort* __restrict__ Wb, const float* __restrict__ SW,
              const float* __restrict__ Bq, float* __restrict__ Out)
{
    __shared__ uint4 smem4[8192];
    char* const smem = (char*)smem4;
    const int tid = threadIdx.x;
    const int d = blockIdx.x;
    const int g = (d & 7) * 128 + (d >> 3);
    const int bn_idx = g & 3, bm_idx = g >> 2;
    const int bm0 = bm_idx * 256, bn0 = bn_idx * 256;
    const float sx = SXp[0], inv_sx = 1.0f / sx;
    const int ar = tid >> 2, ac = (tid & 3) << 4;
    const float* xg = X + (size_t)(bm0 + ar) * K_TOTAL + ac;
    const int awslot = (tid & 3) << 1;
    const int awsw0 = ((awslot    ) ^ (ar & 7)) << 4;
    const int awsw1 = ((awslot + 1) ^ (ar & 7)) << 4;
    const int lane = tid & 63, w = tid >> 6;
    const int wm = (w >> 2) << 7, wn = (w & 3) << 6;
    const int fr = lane & 15, fg = lane >> 4;
    const int s0 = ((fg    ) ^ (fr & 7)) << 4;
    const int s1 = ((fg + 4) ^ (fr & 7)) << 4;
    const int arow = (wm + fr) * 128, brow = (wn + fr) * 128;
    const char* wsrc = (const char*)Wb + (size_t)bn_idx * 16 * 32768
                     + w * 4096 + lane * 16;
    f32x4 acc[8][4] = {};
    float4 xh0[4], xh1[4];
    short8 af[4], bf[4];
    auto issueA = [&](int kt, int h, float4* dst) {
        const float4* p = (const float4*)(xg + (size_t)h * 128 * K_TOTAL + kt * 64);
        dst[0] = p[0]; dst[1] = p[1]; dst[2] = p[2]; dst[3] = p[3];
    };
    auto packA = [&](int buf, int h, const float4* v) {
        unsigned u[8];
        #pragma unroll
        for (int q = 0; q < 4; ++q) {
            u[2*q+0] = pkhi(rintf(v[q].x * inv_sx), rintf(v[q].y * inv_sx));
            u[2*q+1] = pkhi(rintf(v[q].z * inv_sx), rintf(v[q].w * inv_sx));
        }
        char* base = smem + buf * 32768 + (h * 128 + ar) * 128;
        *(uint4*)(base + awsw0) = make_uint4(u[0], u[1], u[2], u[3]);
        *(uint4*)(base + awsw1) = make_uint4(u[4], u[5], u[6], u[7]);
    };
    auto gldsB = [&](int kt, int buf) {
        const char* src = wsrc + (size_t)kt * 32768;
        char* dst = smem + 65536 + buf * 32768 + w * 4096;
        __builtin_amdgcn_global_load_lds((glb_vp*)(src +    0), (lds_vp*)(dst +    0), 16, 0, 0);
        __builtin_amdgcn_global_load_lds((glb_vp*)(src + 1024), (lds_vp*)(dst + 1024), 16, 0, 0);
        __builtin_amdgcn_global_load_lds((glb_vp*)(src + 2048), (lds_vp*)(dst + 2048), 16, 0, 0);
        __builtin_amdgcn_global_load_lds((glb_vp*)(src + 3072), (lds_vp*)(dst + 3072), 16, 0, 0);
    };
    auto readA = [&](int buf, int mh, int sk) {
        const char* base = smem + buf * 32768 + arow;
        #pragma unroll
        for (int i = 0; i < 4; ++i)
            af[i] = *(const short8*)(base + (mh * 64 + i * 16) * 128 + sk);
    };
    auto readB = [&](int buf, int sk) {
        const char* base = smem + 65536 + buf * 32768 + brow;
        #pragma unroll
        for (int j = 0; j < 4; ++j)
            bf[j] = *(const short8*)(base + (j * 16) * 128 + sk);
    };
    auto mfma16 = [&](int mh) {
        __builtin_amdgcn_s_setprio(1);
        #pragma unroll
        for (int i = 0; i < 4; ++i)
            #pragma unroll
            for (int j = 0; j < 4; ++j)
                acc[mh*4+i][j] = __builtin_amdgcn_mfma_f32_16x16x32_bf16(
                    af[i], bf[j], acc[mh*4+i][j], 0, 0, 0);
        __builtin_amdgcn_s_setprio(0);
    };
    issueA(0, 0, xh0); issueA(0, 1, xh1);
    gldsB(0, 0);
    packA(0, 0, xh0); packA(0, 1, xh1);
    issueA(1, 0, xh0); issueA(1, 1, xh1);
    WAITV8(); WAITL0(); BAR();
    for (int t = 0; t < 16; ++t) {
        const int cur = t & 1, nxt = cur ^ 1;
        const bool pf  = (t + 1 < 16);
        const bool pf2 = (t + 2 < 16);
        if (pf) gldsB(t + 1, nxt);
        readA(cur, 0, s0); readB(cur, s0);
        BAR(); mfma16(0); BAR();
        readA(cur, 1, s0);
        BAR(); mfma16(1); BAR();
        if (pf)  packA(nxt, 0, xh0);
        if (pf2) issueA(t + 2, 0, xh0);
        readA(cur, 0, s1); readB(cur, s1);
        BAR(); mfma16(0); BAR();
        if (pf)  packA(nxt, 1, xh1);
        if (pf2) issueA(t + 2, 1, xh1);
        readA(cur, 1, s1);
        BAR(); mfma16(1);
        if (pf) {
            if (pf2) WAITV8(); else WAITV0();
            WAITL0(); BAR();
        }
    }
    #pragma unroll
    for (int n = 0; n < 4; ++n) {
        const int col = bn0 + wn + n * 16 + fr;
        const float sa  = SW[col] * sx;
        const float b32 = rintf(Bq[col] * inv_sx);
        #pragma unroll
        for (int m = 0; m < 8; ++m) {
            const size_t r0 = (size_t)(bm0 + wm + m * 16 + fg * 4) * N_TOTAL + col;
            #pragma unroll
            for (int r = 0; r < 4; ++r)
                Out[r0 + (size_t)r * N_TOTAL] = (acc[m][n][r] + b32) * sa;
        }
    }
}

__global__ void sa_tail(const float* __restrict__ SW, const float* __restrict__ SXp,
                        float* __restrict__ Out)
{
    int o = blockIdx.x * blockDim.x + threadIdx.x;
    if (o < N_TOTAL) Out[(size_t)M_TOTAL * N_TOTAL + o] = SW[o] * SXp[0];
}

extern "C" void kernel_launch(void* const* d_in, const int* in_sizes, int n_in,
                              void* d_out, int out_size, void* d_ws, size_t ws_size,
                              hipStream_t stream)
{
    const float* x  = (const float*)d_in[0];
    const float* sx = (const float*)d_in[1];
    const float* wq = (const float*)d_in[2];
    const float* sw = (const float*)d_in[3];
    const float* bq = (const float*)d_in[4];
    float* out = (float*)d_out;

    const size_t W_BYTES = 1u << 20;          // Wb: 1 MiB
    const size_t X_BYTES = (size_t)64 << 20;  // Xb: 64 MiB

    if (ws_size >= W_BYTES + X_BYTES) {
        char* wbuf = (char*)d_ws;
        char* xbuf = (char*)d_ws + W_BYTES;
        wconv8<<<1024, 256, 0, stream>>>(wq, sx, sw, wbuf, out);
        xconv8<<<16384, 256, 0, stream>>>(x, sx, xbuf);
        qgemm8<<<4096, 256, 0, stream>>>(xbuf, sx, wbuf, sw, bq, out);
    } else {
        ushort* wbuf = (ushort*)d_ws;         // 2 MiB (r5 path)
        wconv_bf<<<1024, 256, 0, stream>>>(wq, wbuf);
        qgemm_bf<<<1024, 512, 0, stream>>>(x, sx, wbuf, sw, bq, out);
        sa_tail<<<4, 256, 0, stream>>>(sw, sx, out);
    }
}

// Round 10
// 221.879 us; speedup vs baseline: 1.1245x; 1.0785x over previous
//
#include <hip/hip_runtime.h>
#include <hip/hip_bf16.h>

#define M_TOTAL 65536
#define N_TOTAL 1024
#define K_TOTAL 1024

typedef __attribute__((ext_vector_type(8))) short short8;
typedef __attribute__((ext_vector_type(4))) float f32x4;
typedef __attribute__((ext_vector_type(4))) int   i32x4;

typedef __attribute__((address_space(3))) void lds_vp;
typedef const __attribute__((address_space(1))) void glb_vp;

#define BAR()    asm volatile("s_barrier" ::: "memory")
#define WAITV8() asm volatile("s_waitcnt vmcnt(8)" ::: "memory")
#define WAITV4() asm volatile("s_waitcnt vmcnt(4)" ::: "memory")
#define WAITV0() asm volatile("s_waitcnt vmcnt(0)" ::: "memory")
#define WAITL0() asm volatile("s_waitcnt lgkmcnt(0)" ::: "memory")

#define MAGIC 12582912.0f   // 1.5*2^23: low byte of (r+MAGIC) = (int8)rint(r)

static __device__ __forceinline__ unsigned fbits(float f) {
    union { float f; unsigned u; } c; c.f = f; return c.u;
}
// pack low bytes of 4 magic-biased floats into one dword (verified r6-r9)
static __device__ __forceinline__ unsigned pk4(float g0, float g1, float g2, float g3) {
    unsigned p01 = __builtin_amdgcn_perm(fbits(g1), fbits(g0), 0x0C0C0400u);
    unsigned p23 = __builtin_amdgcn_perm(fbits(g3), fbits(g2), 0x04000C0Cu);
    return p01 | p23;
}
// non-contracted multiply: keep rint semantics of (v*inv)+MAGIC exact
static __device__ __forceinline__ float mulnc(float a, float b) {
    float t = a * b; asm volatile("" : "+v"(t)); return t;
}
// pack hi16 halves (bf16 of integer-valued f32) — fallback path
static __device__ __forceinline__ unsigned pkhi(float lo, float hi) {
    return __builtin_amdgcn_perm(fbits(hi), fbits(lo), 0x07060302u);
}

// ===================== FAST PATH (i8, glds 3-buffer pipeline) ================
// NEW layout (r10): Xb/Wb are ROW-MAJOR i8 [row][1024], with the bank swizzle
// folded into each 64B group: physical 16B-slot s of row r holds logical slot
// s ^ ((r>>1)&3). kt-independent -> conversion kernels stream at full BW, and
// a linear glds fill reproduces exactly the r9 LDS image (0 conflicts proven).

// W: [1024][1024] f32 ints -> Wb row-major i8 (+ s_a tail). 1024 x 256.
__global__ void wconv8(const float* __restrict__ Wq, const float* __restrict__ SXp,
                       const float* __restrict__ SW, char* __restrict__ Wb,
                       float* __restrict__ Out) {
    const int n = blockIdx.x, t = threadIdx.x;
    float4 v = *(const float4*)(Wq + (size_t)n * K_TOTAL + t * 4);
    unsigned dw = pk4(v.x + MAGIC, v.y + MAGIC, v.z + MAGIC, v.w + MAGIC);
    const int p  = (n >> 1) & 3;
    const int db = t * 4;
    const int phys = (db & ~0x30) | ((((db >> 4) & 3) ^ p) << 4);
    *(unsigned*)(Wb + (size_t)n * 1024 + phys) = dw;
    if (t == 0)
        Out[(size_t)M_TOTAL * N_TOTAL + n] = SW[n] * SXp[0];
}

// X: [65536][1024] f32 -> Xb row-major i8. One wave per row: reads 4KB dense
// (4 x 1KB instrs), writes 1KB dense (4 x 256B dword instrs, slot-permuted).
__global__ __launch_bounds__(256)
void xconv8(const float* __restrict__ X, const float* __restrict__ SXp,
            char* __restrict__ Xb) {
    const float inv_sx = 1.0f / SXp[0];
    const int lane = threadIdx.x & 63;
    const unsigned row = blockIdx.x * 4 + (threadIdx.x >> 6);   // 0..65535
    const float* src = X + (size_t)row * K_TOTAL;
    char* drow = Xb + (size_t)row * 1024;
    const int p = (row >> 1) & 3;
    #pragma unroll
    for (int q = 0; q < 4; ++q) {
        float4 v = *(const float4*)(src + q * 256 + lane * 4);
        unsigned dw = pk4(mulnc(v.x, inv_sx) + MAGIC, mulnc(v.y, inv_sx) + MAGIC,
                          mulnc(v.z, inv_sx) + MAGIC, mulnc(v.w, inv_sx) + MAGIC);
        const int db = q * 256 + lane * 4;
        const int phys = (db & ~0x30) | ((((db >> 4) & 3) ^ p) << 4);
        *(unsigned*)(drow + phys) = dw;
    }
}

// GEMM: 128x128 tile, 4 waves, glds both operands, 3-buffer counted pipeline.
// Unchanged from r9 except glds source addressing (row-major gather).
__global__ __launch_bounds__(256, 3)
void qgemm8(const char* __restrict__ Xb, const float* __restrict__ SXp,
            const char* __restrict__ Wb, const float* __restrict__ SW,
            const float* __restrict__ Bq, float* __restrict__ Out)
{
    __shared__ uint4 smem4[3072];          // 48 KiB: A 3x8K @0, B 3x8K @24576
    char* const smem = (char*)smem4;

    const int d = blockIdx.x;
    const int g = (d & 7) * 512 + (d >> 3);    // XCD-bijective (4096 % 8 == 0)
    const int bn_idx = g & 7, bm_idx = g >> 3;

    const int lane = threadIdx.x & 63, w = threadIdx.x >> 6;
    const int wm = (w >> 1) << 6, wn = (w & 1) << 6;
    const int fr = lane & 15, fg = lane >> 4;
    const int sslot = ((fg ^ ((fr >> 1) & 3)) << 4);
    const int arow = (wm + fr) * 64;
    const int brow = (wn + fr) * 64;

    // glds sources (row-major): wave w covers tile rows w*32..w*32+31.
    // instr i (0/1) adds 16 rows (16384B); kt adds kt*64 within each row.
    const char* asrc = Xb + ((size_t)bm_idx * 128 + w * 32 + (lane >> 2)) * 1024
                          + (lane & 3) * 16;
    const char* bsrc = Wb + ((size_t)bn_idx * 128 + w * 32 + (lane >> 2)) * 1024
                          + (lane & 3) * 16;

    const float sx = SXp[0], inv_sx = 1.0f / sx;

    i32x4 acc[4][4] = {};
    i32x4 af[4], bf[4];

    auto glds = [&](int kt, int buf) {
        const char* sa = asrc + kt * 64;
        const char* sb = bsrc + kt * 64;
        char* da = smem +         buf * 8192 + w * 2048;
        char* db = smem + 24576 + buf * 8192 + w * 2048;
        __builtin_amdgcn_global_load_lds((glb_vp*)(sa +     0), (lds_vp*)(da +    0), 16, 0, 0);
        __builtin_amdgcn_global_load_lds((glb_vp*)(sa + 16384), (lds_vp*)(da + 1024), 16, 0, 0);
        __builtin_amdgcn_global_load_lds((glb_vp*)(sb +     0), (lds_vp*)(db +    0), 16, 0, 0);
        __builtin_amdgcn_global_load_lds((glb_vp*)(sb + 16384), (lds_vp*)(db + 1024), 16, 0, 0);
    };

    // prologue: 2 tiles in flight
    glds(0, 0);
    glds(1, 1);

    #pragma unroll
    for (int t = 0; t < 16; ++t) {
        const int buf = t % 3;
        // retire glds(t) ONLY; glds(t+1) stays in flight across the barrier
        if (t < 15) WAITV4(); else WAITV0();
        BAR();                              // all waves' glds(t) visible
        // WAR-clean: every wave is past its tile t-1 ds_reads before BAR
        if (t + 2 < 16) glds(t + 2, (t + 2) % 3);
        {
            const char* ab = smem +         buf * 8192 + arow + sslot;
            const char* bb = smem + 24576 + buf * 8192 + brow + sslot;
            #pragma unroll
            for (int i = 0; i < 4; ++i)
                af[i] = *(const i32x4*)(ab + (i * 16) * 64);
            #pragma unroll
            for (int j = 0; j < 4; ++j)
                bf[j] = *(const i32x4*)(bb + (j * 16) * 64);
        }
        __builtin_amdgcn_s_setprio(1);
        #pragma unroll
        for (int i = 0; i < 4; ++i)
            #pragma unroll
            for (int j = 0; j < 4; ++j)
                acc[i][j] = __builtin_amdgcn_mfma_i32_16x16x64_i8(
                    af[i], bf[j], acc[i][j], 0, 0, 0);
        __builtin_amdgcn_s_setprio(0);
    }

    // epilogue: (acc_i32 + rint(b/s_x)) * (s_w*s_x); exact (|acc|+|b32| < 2^24)
    // C/D layout: col = lane&15, row = (lane>>4)*4 + r
    const int bm0 = bm_idx * 128, bn0 = bn_idx * 128;
    #pragma unroll
    for (int n = 0; n < 4; ++n) {
        const int col = bn0 + wn + n * 16 + fr;
        const float sa  = SW[col] * sx;
        const float b32 = rintf(Bq[col] * inv_sx);
        #pragma unroll
        for (int m = 0; m < 4; ++m) {
            const size_t r0 = (size_t)(bm0 + wm + m * 16 + fg * 4) * N_TOTAL + col;
            #pragma unroll
            for (int r = 0; r < 4; ++r)
                Out[r0 + (size_t)r * N_TOTAL] = ((float)acc[m][n][r] + b32) * sa;
        }
    }
}

// ===================== FALLBACK (r5 bf16 kernel, 221us) ======================
__global__ void wconv_bf(const float* __restrict__ Wq, ushort* __restrict__ Wb) {
    const int n = blockIdx.x, c4 = threadIdx.x * 4;
    float4 v = *(const float4*)(Wq + (size_t)n * K_TOTAL + c4);
    const int bnb = n >> 8, row = n & 255, kt = c4 >> 6, c = c4 & 63;
    const int cs = c ^ ((row & 7) << 3);
    ushort* dst = Wb + ((size_t)(bnb * 16 + kt) * 16384 + row * 64 + cs);
    *(uint2*)dst = make_uint2(pkhi(v.x, v.y), pkhi(v.z, v.w));
}

__global__ __launch_bounds__(512, 2)
void qgemm_bf(const float* __restrict__ X, const float* __restrict__ SXp,
              const ushort* __restrict__ Wb, const float* __restrict__ SW,
              const float* __restrict__ Bq, float* __restrict__ Out)
{
    __shared__ uint4 smem4[8192];
    char* const smem = (char*)smem4;
    const int tid = threadIdx.x;
    const int d = blockIdx.x;
    const int g = (d & 7) * 128 + (d >> 3);
    const int bn_idx = g & 3, bm_idx = g >> 2;
    const int bm0 = bm_idx * 256, bn0 = bn_idx * 256;
    const float sx = SXp[0], inv_sx = 1.0f / sx;
    const int ar = tid >> 2, ac = (tid & 3) << 4;
    const float* xg = X + (size_t)(bm0 + ar) * K_TOTAL + ac;
    const int awslot = (tid & 3) << 1;
    const int awsw0 = ((awslot    ) ^ (ar & 7)) << 4;
    const int awsw1 = ((awslot + 1) ^ (ar & 7)) << 4;
    const int lane = tid & 63, w = tid >> 6;
    const int wm = (w >> 2) << 7, wn = (w & 3) << 6;
    const int fr = lane & 15, fg = lane >> 4;
    const int s0 = ((fg    ) ^ (fr & 7)) << 4;
    const int s1 = ((fg + 4) ^ (fr & 7)) << 4;
    const int arow = (wm + fr) * 128, brow = (wn + fr) * 128;
    const char* wsrc = (const char*)Wb + (size_t)bn_idx * 16 * 32768
                     + w * 4096 + lane * 16;
    f32x4 acc[8][4] = {};
    float4 xh0[4], xh1[4];
    short8 af[4], bf[4];
    auto issueA = [&](int kt, int h, float4* dst) {
        const float4* p = (const float4*)(xg + (size_t)h * 128 * K_TOTAL + kt * 64);
        dst[0] = p[0]; dst[1] = p[1]; dst[2] = p[2]; dst[3] = p[3];
    };
    auto packA = [&](int buf, int h, const float4* v) {
        unsigned u[8];
        #pragma unroll
        for (int q = 0; q < 4; ++q) {
            u[2*q+0] = pkhi(rintf(v[q].x * inv_sx), rintf(v[q].y * inv_sx));
            u[2*q+1] = pkhi(rintf(v[q].z * inv_sx), rintf(v[q].w * inv_sx));
        }
        char* base = smem + buf * 32768 + (h * 128 + ar) * 128;
        *(uint4*)(base + awsw0) = make_uint4(u[0], u[1], u[2], u[3]);
        *(uint4*)(base + awsw1) = make_uint4(u[4], u[5], u[6], u[7]);
    };
    auto gldsB = [&](int kt, int buf) {
        const char* src = wsrc + (size_t)kt * 32768;
        char* dst = smem + 65536 + buf * 32768 + w * 4096;
        __builtin_amdgcn_global_load_lds((glb_vp*)(src +    0), (lds_vp*)(dst +    0), 16, 0, 0);
        __builtin_amdgcn_global_load_lds((glb_vp*)(src + 1024), (lds_vp*)(dst + 1024), 16, 0, 0);
        __builtin_amdgcn_global_load_lds((glb_vp*)(src + 2048), (lds_vp*)(dst + 2048), 16, 0, 0);
        __builtin_amdgcn_global_load_lds((glb_vp*)(src + 3072), (lds_vp*)(dst + 3072), 16, 0, 0);
    };
    auto readA = [&](int buf, int mh, int sk) {
        const char* base = smem + buf * 32768 + arow;
        #pragma unroll
        for (int i = 0; i < 4; ++i)
            af[i] = *(const short8*)(base + (mh * 64 + i * 16) * 128 + sk);
    };
    auto readB = [&](int buf, int sk) {
        const char* base = smem + 65536 + buf * 32768 + brow;
        #pragma unroll
        for (int j = 0; j < 4; ++j)
            bf[j] = *(const short8*)(base + (j * 16) * 128 + sk);
    };
    auto mfma16 = [&](int mh) {
        __builtin_amdgcn_s_setprio(1);
        #pragma unroll
        for (int i = 0; i < 4; ++i)
            #pragma unroll
            for (int j = 0; j < 4; ++j)
                acc[mh*4+i][j] = __builtin_amdgcn_mfma_f32_16x16x32_bf16(
                    af[i], bf[j], acc[mh*4+i][j], 0, 0, 0);
        __builtin_amdgcn_s_setprio(0);
    };
    issueA(0, 0, xh0); issueA(0, 1, xh1);
    gldsB(0, 0);
    packA(0, 0, xh0); packA(0, 1, xh1);
    issueA(1, 0, xh0); issueA(1, 1, xh1);
    WAITV8(); WAITL0(); BAR();
    for (int t = 0; t < 16; ++t) {
        const int cur = t & 1, nxt = cur ^ 1;
        const bool pf  = (t + 1 < 16);
        const bool pf2 = (t + 2 < 16);
        if (pf) gldsB(t + 1, nxt);
        readA(cur, 0, s0); readB(cur, s0);
        BAR(); mfma16(0); BAR();
        readA(cur, 1, s0);
        BAR(); mfma16(1); BAR();
        if (pf)  packA(nxt, 0, xh0);
        if (pf2) issueA(t + 2, 0, xh0);
        readA(cur, 0, s1); readB(cur, s1);
        BAR(); mfma16(0); BAR();
        if (pf)  packA(nxt, 1, xh1);
        if (pf2) issueA(t + 2, 1, xh1);
        readA(cur, 1, s1);
        BAR(); mfma16(1);
        if (pf) {
            if (pf2) WAITV8(); else WAITV0();
            WAITL0(); BAR();
        }
    }
    #pragma unroll
    for (int n = 0; n < 4; ++n) {
        const int col = bn0 + wn + n * 16 + fr;
        const float sa  = SW[col] * sx;
        const float b32 = rintf(Bq[col] * inv_sx);
        #pragma unroll
        for (int m = 0; m < 8; ++m) {
            const size_t r0 = (size_t)(bm0 + wm + m * 16 + fg * 4) * N_TOTAL + col;
            #pragma unroll
            for (int r = 0; r < 4; ++r)
                Out[r0 + (size_t)r * N_TOTAL] = (acc[m][n][r] + b32) * sa;
        }
    }
}

__global__ void sa_tail(const float* __restrict__ SW, const float* __restrict__ SXp,
                        float* __restrict__ Out)
{
    int o = blockIdx.x * blockDim.x + threadIdx.x;
    if (o < N_TOTAL) Out[(size_t)M_TOTAL * N_TOTAL + o] = SW[o] * SXp[0];
}

extern "C" void kernel_launch(void* const* d_in, const int* in_sizes, int n_in,
                              void* d_out, int out_size, void* d_ws, size_t ws_size,
                              hipStream_t stream)
{
    const float* x  = (const float*)d_in[0];
    const float* sx = (const float*)d_in[1];
    const float* wq = (const float*)d_in[2];
    const float* sw = (const float*)d_in[3];
    const float* bq = (const float*)d_in[4];
    float* out = (float*)d_out;

    const size_t W_BYTES = 1u << 20;          // Wb: 1 MiB
    const size_t X_BYTES = (size_t)64 << 20;  // Xb: 64 MiB

    if (ws_size >= W_BYTES + X_BYTES) {
        char* wbuf = (char*)d_ws;
        char* xbuf = (char*)d_ws + W_BYTES;
        wconv8<<<1024, 256, 0, stream>>>(wq, sx, sw, wbuf, out);
        xconv8<<<16384, 256, 0, stream>>>(x, sx, xbuf);
        qgemm8<<<4096, 256, 0, stream>>>(xbuf, sx, wbuf, sw, bq, out);
    } else {
        ushort* wbuf = (ushort*)d_ws;         // 2 MiB (r5 path)
        wconv_bf<<<1024, 256, 0, stream>>>(wq, wbuf);
        qgemm_bf<<<1024, 512, 0, stream>>>(x, sx, wbuf, sw, bq, out);
        sa_tail<<<4, 256, 0, stream>>>(sw, sx, out);
    }
}

// Round 11
// 211.498 us; speedup vs baseline: 1.1797x; 1.0491x over previous
//
#include <hip/hip_runtime.h>
#include <hip/hip_bf16.h>

#define M_TOTAL 65536
#define N_TOTAL 1024
#define K_TOTAL 1024

typedef __attribute__((ext_vector_type(8))) short short8;
typedef __attribute__((ext_vector_type(4))) float f32x4;
typedef __attribute__((ext_vector_type(4))) int   i32x4;

typedef __attribute__((address_space(3))) void lds_vp;
typedef const __attribute__((address_space(1))) void glb_vp;

#define BAR()    asm volatile("s_barrier" ::: "memory")
#define WAITV8() asm volatile("s_waitcnt vmcnt(8)" ::: "memory")
#define WAITV0() asm volatile("s_waitcnt vmcnt(0)" ::: "memory")
#define WAITL0() asm volatile("s_waitcnt lgkmcnt(0)" ::: "memory")

#define MAGIC 12582912.0f   // 1.5*2^23: low byte of (r+MAGIC) = (int8)rint(r)

static __device__ __forceinline__ unsigned fbits(float f) {
    union { float f; unsigned u; } c; c.f = f; return c.u;
}
// pack low bytes of 4 magic-biased floats into one dword (verified r6-r10)
static __device__ __forceinline__ unsigned pk4(float g0, float g1, float g2, float g3) {
    unsigned p01 = __builtin_amdgcn_perm(fbits(g1), fbits(g0), 0x0C0C0400u);
    unsigned p23 = __builtin_amdgcn_perm(fbits(g3), fbits(g2), 0x04000C0Cu);
    return p01 | p23;
}
// non-contracted multiply: keep rint semantics of (v*inv)+MAGIC exact
static __device__ __forceinline__ float mulnc(float a, float b) {
    float t = a * b; asm volatile("" : "+v"(t)); return t;
}
// pack hi16 halves (bf16 of integer-valued f32) — fallback path
static __device__ __forceinline__ unsigned pkhi(float lo, float hi) {
    return __builtin_amdgcn_perm(fbits(hi), fbits(lo), 0x07060302u);
}

// ===================== FAST PATH (i8) ========================================
// Xb/Wb: ROW-MAJOR i8 [row][1024], bank swizzle folded into each 64B group:
// physical 16B-slot s of row r holds logical slot s ^ ((r>>1)&3).
// (r10 layout, kt-independent; linear glds fill -> 0-conflict LDS image.)

// W: [1024][1024] f32 ints -> Wb row-major i8 (+ s_a tail). 1024 x 256.
__global__ void wconv8(const float* __restrict__ Wq, const float* __restrict__ SXp,
                       const float* __restrict__ SW, char* __restrict__ Wb,
                       float* __restrict__ Out) {
    const int n = blockIdx.x, t = threadIdx.x;
    float4 v = *(const float4*)(Wq + (size_t)n * K_TOTAL + t * 4);
    unsigned dw = pk4(v.x + MAGIC, v.y + MAGIC, v.z + MAGIC, v.w + MAGIC);
    const int p  = (n >> 1) & 3;
    const int db = t * 4;
    const int phys = (db & ~0x30) | ((((db >> 4) & 3) ^ p) << 4);
    *(unsigned*)(Wb + (size_t)n * 1024 + phys) = dw;
    if (t == 0)
        Out[(size_t)M_TOTAL * N_TOTAL + n] = SW[n] * SXp[0];
}

// X: [65536][1024] f32 -> Xb row-major i8. One wave per row (dense stream).
__global__ __launch_bounds__(256)
void xconv8(const float* __restrict__ X, const float* __restrict__ SXp,
            char* __restrict__ Xb) {
    const float inv_sx = 1.0f / SXp[0];
    const int lane = threadIdx.x & 63;
    const unsigned row = blockIdx.x * 4 + (threadIdx.x >> 6);   // 0..65535
    const float* src = X + (size_t)row * K_TOTAL;
    char* drow = Xb + (size_t)row * 1024;
    const int p = (row >> 1) & 3;
    #pragma unroll
    for (int q = 0; q < 4; ++q) {
        float4 v = *(const float4*)(src + q * 256 + lane * 4);
        unsigned dw = pk4(mulnc(v.x, inv_sx) + MAGIC, mulnc(v.y, inv_sx) + MAGIC,
                          mulnc(v.z, inv_sx) + MAGIC, mulnc(v.w, inv_sx) + MAGIC);
        const int db = q * 256 + lane * 4;
        const int phys = (db & ~0x30) | ((((db >> 4) & 3) ^ p) << 4);
        *(unsigned*)(drow + phys) = dw;
    }
}

// GEMM r11: 128x256 tile, 8 waves (2Mx4N, 64x64/wave), BK=64, dbuf LDS,
// 2 phases/K-tile, counted tile-end wait. 48 KiB LDS + <=128 VGPR ->
// 2 blocks/CU = 16 waves/CU (4/SIMD) for cross-block stall absorption.
__global__ __launch_bounds__(512, 4)
void qgemm8(const char* __restrict__ Xb, const float* __restrict__ SXp,
            const char* __restrict__ Wb, const float* __restrict__ SW,
            const float* __restrict__ Bq, float* __restrict__ Out)
{
    __shared__ uint4 smem4[3072];   // 48 KiB: A dbuf 2x8K @0, B dbuf 2x16K @16384
    char* const smem = (char*)smem4;

    const int tid = threadIdx.x;
    const int d = blockIdx.x;                    // 2048 blocks, 2048%8==0
    const int g = (d & 7) * 256 + (d >> 3);      // XCD-bijective
    const int bn_idx = g & 3, bm_idx = g >> 2;   // 4 bn-sharers same XCD

    const int lane = tid & 63, w = tid >> 6;     // 8 waves
    const int wm = (w >> 2) << 6;                // 0 / 64
    const int wn = (w & 3) << 6;                 // 0..192
    const int fr = lane & 15, fg = lane >> 4;
    const int sslot = ((fg ^ ((fr >> 1) & 3)) << 4);
    const int arow = (wm + fr) * 64;
    const int brow = (wn + fr) * 64;

    // glds sources (row-major, pre-swizzled). A: wave w fills LDS rows
    // w*16..w*16+15 (1 instr). B: rows w*32..w*32+31 (2 instrs).
    const char* asrc = Xb + ((size_t)bm_idx * 128 + w * 16 + (lane >> 2)) * 1024
                          + (lane & 3) * 16;
    const char* bsrc = Wb + ((size_t)bn_idx * 256 + w * 32 + (lane >> 2)) * 1024
                          + (lane & 3) * 16;

    const float sx = SXp[0], inv_sx = 1.0f / sx;

    i32x4 acc[4][4] = {};
    i32x4 af[4], bf[4];

    auto gldsA = [&](int kt, int buf) {
        char* da = smem + buf * 8192 + w * 1024;
        __builtin_amdgcn_global_load_lds((glb_vp*)(asrc + kt * 64), (lds_vp*)da, 16, 0, 0);
    };
    auto gldsB = [&](int kt, int buf, int i) {   // i = 0/1 (16 rows each)
        char* db = smem + 16384 + buf * 16384 + w * 2048 + i * 1024;
        __builtin_amdgcn_global_load_lds((glb_vp*)(bsrc + i * 16384 + kt * 64),
                                         (lds_vp*)db, 16, 0, 0);
    };
    auto readA = [&](int buf) {
        const char* ab = smem + buf * 8192 + arow + sslot;
        #pragma unroll
        for (int i = 0; i < 4; ++i)
            af[i] = *(const i32x4*)(ab + (i * 16) * 64);
    };
    auto readBh = [&](int buf, int jh) {         // bf[2jh], bf[2jh+1]
        const char* bb = smem + 16384 + buf * 16384 + brow + sslot;
        bf[jh*2+0] = *(const i32x4*)(bb + ((jh*2+0) * 16) * 64);
        bf[jh*2+1] = *(const i32x4*)(bb + ((jh*2+1) * 16) * 64);
    };
    auto mfma8 = [&](int jh) {                   // 8 MFMA: all m x {2jh,2jh+1}
        __builtin_amdgcn_s_setprio(1);
        #pragma unroll
        for (int i = 0; i < 4; ++i)
            #pragma unroll
            for (int j = 0; j < 2; ++j)
                acc[i][jh*2+j] = __builtin_amdgcn_mfma_i32_16x16x64_i8(
                    af[i], bf[jh*2+j], acc[i][jh*2+j], 0, 0, 0);
        __builtin_amdgcn_s_setprio(0);
    };

    // prologue: stage tile 0
    gldsA(0, 0); gldsB(0, 0, 0); gldsB(0, 0, 1);
    WAITV0();
    BAR();

    #pragma unroll
    for (int t = 0; t < 16; ++t) {
        const int cur = t & 1, nxt = cur ^ 1;
        const bool pf = (t + 1 < 16);
        // ---- P0: reads + stage(t+1) A,B0; MFMA j=0,1 ----
        readA(cur); readBh(cur, 0);
        if (pf) { gldsA(t + 1, nxt); gldsB(t + 1, nxt, 0); }
        BAR();
        mfma8(0);
        BAR();
        // ---- P1: reads B-half 1 + stage(t+1) B1; MFMA j=2,3 ----
        readBh(cur, 1);
        if (pf) gldsB(t + 1, nxt, 1);
        BAR();
        mfma8(1);
        if (pf) {
            WAITV0();       // retire glds(t+1): 3 ops, issued 1-2 phases ago
            BAR();
        }
    }

    // epilogue: (acc_i32 + rint(b/s_x)) * (s_w*s_x); exact (|acc|+|b32| < 2^24)
    // C/D layout: col = lane&15, row = (lane>>4)*4 + r
    const int bm0 = bm_idx * 128, bn0 = bn_idx * 256;
    #pragma unroll
    for (int n = 0; n < 4; ++n) {
        const int col = bn0 + wn + n * 16 + fr;
        const float sa  = SW[col] * sx;
        const float b32 = rintf(Bq[col] * inv_sx);
        #pragma unroll
        for (int m = 0; m < 4; ++m) {
            const size_t r0 = (size_t)(bm0 + wm + m * 16 + fg * 4) * N_TOTAL + col;
            #pragma unroll
            for (int r = 0; r < 4; ++r)
                Out[r0 + (size_t)r * N_TOTAL] = ((float)acc[m][n][r] + b32) * sa;
        }
    }
}

// ===================== FALLBACK (r5 bf16 kernel, 221us) ======================
__global__ void wconv_bf(const float* __restrict__ Wq, ushort* __restrict__ Wb) {
    const int n = blockIdx.x, c4 = threadIdx.x * 4;
    float4 v = *(const float4*)(Wq + (size_t)n * K_TOTAL + c4);
    const int bnb = n >> 8, row = n & 255, kt = c4 >> 6, c = c4 & 63;
    const int cs = c ^ ((row & 7) << 3);
    ushort* dst = Wb + ((size_t)(bnb * 16 + kt) * 16384 + row * 64 + cs);
    *(uint2*)dst = make_uint2(pkhi(v.x, v.y), pkhi(v.z, v.w));
}

__global__ __launch_bounds__(512, 2)
void qgemm_bf(const float* __restrict__ X, const float* __restrict__ SXp,
              const ushort* __restrict__ Wb, const float* __restrict__ SW,
              const float* __restrict__ Bq, float* __restrict__ Out)
{
    __shared__ uint4 smem4[8192];
    char* const smem = (char*)smem4;
    const int tid = threadIdx.x;
    const int d = blockIdx.x;
    const int g = (d & 7) * 128 + (d >> 3);
    const int bn_idx = g & 3, bm_idx = g >> 2;
    const int bm0 = bm_idx * 256, bn0 = bn_idx * 256;
    const float sx = SXp[0], inv_sx = 1.0f / sx;
    const int ar = tid >> 2, ac = (tid & 3) << 4;
    const float* xg = X + (size_t)(bm0 + ar) * K_TOTAL + ac;
    const int awslot = (tid & 3) << 1;
    const int awsw0 = ((awslot    ) ^ (ar & 7)) << 4;
    const int awsw1 = ((awslot + 1) ^ (ar & 7)) << 4;
    const int lane = tid & 63, w = tid >> 6;
    const int wm = (w >> 2) << 7, wn = (w & 3) << 6;
    const int fr = lane & 15, fg = lane >> 4;
    const int s0 = ((fg    ) ^ (fr & 7)) << 4;
    const int s1 = ((fg + 4) ^ (fr & 7)) << 4;
    const int arow = (wm + fr) * 128, brow = (wn + fr) * 128;
    const char* wsrc = (const char*)Wb + (size_t)bn_idx * 16 * 32768
                     + w * 4096 + lane * 16;
    f32x4 acc[8][4] = {};
    float4 xh0[4], xh1[4];
    short8 af[4], bf[4];
    auto issueA = [&](int kt, int h, float4* dst) {
        const float4* p = (const float4*)(xg + (size_t)h * 128 * K_TOTAL + kt * 64);
        dst[0] = p[0]; dst[1] = p[1]; dst[2] = p[2]; dst[3] = p[3];
    };
    auto packA = [&](int buf, int h, const float4* v) {
        unsigned u[8];
        #pragma unroll
        for (int q = 0; q < 4; ++q) {
            u[2*q+0] = pkhi(rintf(v[q].x * inv_sx), rintf(v[q].y * inv_sx));
            u[2*q+1] = pkhi(rintf(v[q].z * inv_sx), rintf(v[q].w * inv_sx));
        }
        char* base = smem + buf * 32768 + (h * 128 + ar) * 128;
        *(uint4*)(base + awsw0) = make_uint4(u[0], u[1], u[2], u[3]);
        *(uint4*)(base + awsw1) = make_uint4(u[4], u[5], u[6], u[7]);
    };
    auto gldsB = [&](int kt, int buf) {
        const char* src = wsrc + (size_t)kt * 32768;
        char* dst = smem + 65536 + buf * 32768 + w * 4096;
        __builtin_amdgcn_global_load_lds((glb_vp*)(src +    0), (lds_vp*)(dst +    0), 16, 0, 0);
        __builtin_amdgcn_global_load_lds((glb_vp*)(src + 1024), (lds_vp*)(dst + 1024), 16, 0, 0);
        __builtin_amdgcn_global_load_lds((glb_vp*)(src + 2048), (lds_vp*)(dst + 2048), 16, 0, 0);
        __builtin_amdgcn_global_load_lds((glb_vp*)(src + 3072), (lds_vp*)(dst + 3072), 16, 0, 0);
    };
    auto readA = [&](int buf, int mh, int sk) {
        const char* base = smem + buf * 32768 + arow;
        #pragma unroll
        for (int i = 0; i < 4; ++i)
            af[i] = *(const short8*)(base + (mh * 64 + i * 16) * 128 + sk);
    };
    auto readB = [&](int buf, int sk) {
        const char* base = smem + 65536 + buf * 32768 + brow;
        #pragma unroll
        for (int j = 0; j < 4; ++j)
            bf[j] = *(const short8*)(base + (j * 16) * 128 + sk);
    };
    auto mfma16 = [&](int mh) {
        __builtin_amdgcn_s_setprio(1);
        #pragma unroll
        for (int i = 0; i < 4; ++i)
            #pragma unroll
            for (int j = 0; j < 4; ++j)
                acc[mh*4+i][j] = __builtin_amdgcn_mfma_f32_16x16x32_bf16(
                    af[i], bf[j], acc[mh*4+i][j], 0, 0, 0);
        __builtin_amdgcn_s_setprio(0);
    };
    issueA(0, 0, xh0); issueA(0, 1, xh1);
    gldsB(0, 0);
    packA(0, 0, xh0); packA(0, 1, xh1);
    issueA(1, 0, xh0); issueA(1, 1, xh1);
    WAITV8(); WAITL0(); BAR();
    for (int t = 0; t < 16; ++t) {
        const int cur = t & 1, nxt = cur ^ 1;
        const bool pf  = (t + 1 < 16);
        const bool pf2 = (t + 2 < 16);
        if (pf) gldsB(t + 1, nxt);
        readA(cur, 0, s0); readB(cur, s0);
        BAR(); mfma16(0); BAR();
        readA(cur, 1, s0);
        BAR(); mfma16(1); BAR();
        if (pf)  packA(nxt, 0, xh0);
        if (pf2) issueA(t + 2, 0, xh0);
        readA(cur, 0, s1); readB(cur, s1);
        BAR(); mfma16(0); BAR();
        if (pf)  packA(nxt, 1, xh1);
        if (pf2) issueA(t + 2, 1, xh1);
        readA(cur, 1, s1);
        BAR(); mfma16(1);
        if (pf) {
            if (pf2) WAITV8(); else WAITV0();
            WAITL0(); BAR();
        }
    }
    #pragma unroll
    for (int n = 0; n < 4; ++n) {
        const int col = bn0 + wn + n * 16 + fr;
        const float sa  = SW[col] * sx;
        const float b32 = rintf(Bq[col] * inv_sx);
        #pragma unroll
        for (int m = 0; m < 8; ++m) {
            const size_t r0 = (size_t)(bm0 + wm + m * 16 + fg * 4) * N_TOTAL + col;
            #pragma unroll
            for (int r = 0; r < 4; ++r)
                Out[r0 + (size_t)r * N_TOTAL] = (acc[m][n][r] + b32) * sa;
        }
    }
}

__global__ void sa_tail(const float* __restrict__ SW, const float* __restrict__ SXp,
                        float* __restrict__ Out)
{
    int o = blockIdx.x * blockDim.x + threadIdx.x;
    if (o < N_TOTAL) Out[(size_t)M_TOTAL * N_TOTAL + o] = SW[o] * SXp[0];
}

extern "C" void kernel_launch(void* const* d_in, const int* in_sizes, int n_in,
                              void* d_out, int out_size, void* d_ws, size_t ws_size,
                              hipStream_t stream)
{
    const float* x  = (const float*)d_in[0];
    const float* sx = (const float*)d_in[1];
    const float* wq = (const float*)d_in[2];
    const float* sw = (const float*)d_in[3];
    const float* bq = (const float*)d_in[4];
    float* out = (float*)d_out;

    const size_t W_BYTES = 1u << 20;          // Wb: 1 MiB
    const size_t X_BYTES = (size_t)64 << 20;  // Xb: 64 MiB

    if (ws_size >= W_BYTES + X_BYTES) {
        char* wbuf = (char*)d_ws;
        char* xbuf = (char*)d_ws + W_BYTES;
        wconv8<<<1024, 256, 0, stream>>>(wq, sx, sw, wbuf, out);
        xconv8<<<16384, 256, 0, stream>>>(x, sx, xbuf);
        qgemm8<<<2048, 512, 0, stream>>>(xbuf, sx, wbuf, sw, bq, out);
    } else {
        ushort* wbuf = (ushort*)d_ws;         // 2 MiB (r5 path)
        wconv_bf<<<1024, 256, 0, stream>>>(wq, wbuf);
        qgemm_bf<<<1024, 512, 0, stream>>>(x, sx, wbuf, sw, bq, out);
        sa_tail<<<4, 256, 0, stream>>>(sw, sx, out);
    }
}

// Round 12
// 210.459 us; speedup vs baseline: 1.1855x; 1.0049x over previous
//
#include <hip/hip_runtime.h>
#include <hip/hip_bf16.h>

#define M_TOTAL 65536
#define N_TOTAL 1024
#define K_TOTAL 1024

typedef __attribute__((ext_vector_type(8))) short short8;
typedef __attribute__((ext_vector_type(4))) float f32x4;
typedef __attribute__((ext_vector_type(4))) int   i32x4;

typedef __attribute__((address_space(3))) void lds_vp;
typedef const __attribute__((address_space(1))) void glb_vp;

#define BAR()    asm volatile("s_barrier" ::: "memory")
#define WAITV8() asm volatile("s_waitcnt vmcnt(8)" ::: "memory")
#define WAITV3() asm volatile("s_waitcnt vmcnt(3)" ::: "memory")
#define WAITV0() asm volatile("s_waitcnt vmcnt(0)" ::: "memory")
#define WAITL0() asm volatile("s_waitcnt lgkmcnt(0)" ::: "memory")

#define MAGIC 12582912.0f   // 1.5*2^23: low byte of (r+MAGIC) = (int8)rint(r)

static __device__ __forceinline__ unsigned fbits(float f) {
    union { float f; unsigned u; } c; c.f = f; return c.u;
}
// pack low bytes of 4 magic-biased floats into one dword (verified r6-r11)
static __device__ __forceinline__ unsigned pk4(float g0, float g1, float g2, float g3) {
    unsigned p01 = __builtin_amdgcn_perm(fbits(g1), fbits(g0), 0x0C0C0400u);
    unsigned p23 = __builtin_amdgcn_perm(fbits(g3), fbits(g2), 0x04000C0Cu);
    return p01 | p23;
}
// non-contracted multiply: keep rint semantics of (v*inv)+MAGIC exact
static __device__ __forceinline__ float mulnc(float a, float b) {
    float t = a * b; asm volatile("" : "+v"(t)); return t;
}
// pack hi16 halves (bf16 of integer-valued f32) — fallback path
static __device__ __forceinline__ unsigned pkhi(float lo, float hi) {
    return __builtin_amdgcn_perm(fbits(hi), fbits(lo), 0x07060302u);
}

// ===================== FAST PATH (i8) ========================================
// Xb/Wb: ROW-MAJOR i8 [row][1024], bank swizzle folded into each 64B group:
// physical 16B-slot s of row r holds logical slot s ^ ((r>>1)&3).
// (r10 layout, kt-independent; linear glds fill -> 0-conflict LDS image.)

// W: [1024][1024] f32 ints -> Wb row-major i8 (+ s_a tail). 1024 x 256.
__global__ void wconv8(const float* __restrict__ Wq, const float* __restrict__ SXp,
                       const float* __restrict__ SW, char* __restrict__ Wb,
                       float* __restrict__ Out) {
    const int n = blockIdx.x, t = threadIdx.x;
    float4 v = *(const float4*)(Wq + (size_t)n * K_TOTAL + t * 4);
    unsigned dw = pk4(v.x + MAGIC, v.y + MAGIC, v.z + MAGIC, v.w + MAGIC);
    const int p  = (n >> 1) & 3;
    const int db = t * 4;
    const int phys = (db & ~0x30) | ((((db >> 4) & 3) ^ p) << 4);
    *(unsigned*)(Wb + (size_t)n * 1024 + phys) = dw;
    if (t == 0)
        Out[(size_t)M_TOTAL * N_TOTAL + n] = SW[n] * SXp[0];
}

// X: [65536][1024] f32 -> Xb row-major i8. One wave per row (dense stream).
__global__ __launch_bounds__(256)
void xconv8(const float* __restrict__ X, const float* __restrict__ SXp,
            char* __restrict__ Xb) {
    const float inv_sx = 1.0f / SXp[0];
    const int lane = threadIdx.x & 63;
    const unsigned row = blockIdx.x * 4 + (threadIdx.x >> 6);   // 0..65535
    const float* src = X + (size_t)row * K_TOTAL;
    char* drow = Xb + (size_t)row * 1024;
    const int p = (row >> 1) & 3;
    #pragma unroll
    for (int q = 0; q < 4; ++q) {
        float4 v = *(const float4*)(src + q * 256 + lane * 4);
        unsigned dw = pk4(mulnc(v.x, inv_sx) + MAGIC, mulnc(v.y, inv_sx) + MAGIC,
                          mulnc(v.z, inv_sx) + MAGIC, mulnc(v.w, inv_sx) + MAGIC);
        const int db = q * 256 + lane * 4;
        const int phys = (db & ~0x30) | ((((db >> 4) & 3) ^ p) << 4);
        *(unsigned*)(drow + phys) = dw;
    }
}

// GEMM r12: 128x256 tile, 8 waves (2Mx4N), BK=64, 2 phases/K-tile,
// 3-BUFFER LDS + COUNTED vmcnt(3): glds issued 2 tiles ahead, never drained
// in the main loop. 72 KiB LDS x 2 blocks/CU = 16 waves/CU.
__global__ __launch_bounds__(512, 4)
void qgemm8(const char* __restrict__ Xb, const float* __restrict__ SXp,
            const char* __restrict__ Wb, const float* __restrict__ SW,
            const float* __restrict__ Bq, float* __restrict__ Out)
{
    __shared__ uint4 smem4[4608];   // 72 KiB: A 3x8K @0, B 3x16K @24576
    char* const smem = (char*)smem4;

    const int tid = threadIdx.x;
    const int d = blockIdx.x;                    // 2048 blocks, 2048%8==0
    const int g = (d & 7) * 256 + (d >> 3);      // XCD-bijective
    const int bn_idx = g & 3, bm_idx = g >> 2;   // 4 bn-sharers same XCD

    const int lane = tid & 63, w = tid >> 6;     // 8 waves
    const int wm = (w >> 2) << 6;                // 0 / 64
    const int wn = (w & 3) << 6;                 // 0..192
    const int fr = lane & 15, fg = lane >> 4;
    const int sslot = ((fg ^ ((fr >> 1) & 3)) << 4);
    const int arow = (wm + fr) * 64;
    const int brow = (wn + fr) * 64;

    // glds sources (row-major, pre-swizzled). A: wave w fills LDS rows
    // w*16..w*16+15 (1 instr). B: rows w*32..w*32+31 (2 instrs).
    const char* asrc = Xb + ((size_t)bm_idx * 128 + w * 16 + (lane >> 2)) * 1024
                          + (lane & 3) * 16;
    const char* bsrc = Wb + ((size_t)bn_idx * 256 + w * 32 + (lane >> 2)) * 1024
                          + (lane & 3) * 16;

    const float sx = SXp[0], inv_sx = 1.0f / sx;

    i32x4 acc[4][4] = {};
    i32x4 af[4], bf[4];

    auto gldsA = [&](int kt, int buf) {
        char* da = smem + buf * 8192 + w * 1024;
        __builtin_amdgcn_global_load_lds((glb_vp*)(asrc + kt * 64), (lds_vp*)da, 16, 0, 0);
    };
    auto gldsB = [&](int kt, int buf, int i) {   // i = 0/1 (16 rows each)
        char* db = smem + 24576 + buf * 16384 + w * 2048 + i * 1024;
        __builtin_amdgcn_global_load_lds((glb_vp*)(bsrc + i * 16384 + kt * 64),
                                         (lds_vp*)db, 16, 0, 0);
    };
    auto readA = [&](int buf) {
        const char* ab = smem + buf * 8192 + arow + sslot;
        #pragma unroll
        for (int i = 0; i < 4; ++i)
            af[i] = *(const i32x4*)(ab + (i * 16) * 64);
    };
    auto readBh = [&](int buf, int jh) {         // bf[2jh], bf[2jh+1]
        const char* bb = smem + 24576 + buf * 16384 + brow + sslot;
        bf[jh*2+0] = *(const i32x4*)(bb + ((jh*2+0) * 16) * 64);
        bf[jh*2+1] = *(const i32x4*)(bb + ((jh*2+1) * 16) * 64);
    };
    auto mfma8 = [&](int jh) {                   // 8 MFMA: all m x {2jh,2jh+1}
        __builtin_amdgcn_s_setprio(1);
        #pragma unroll
        for (int i = 0; i < 4; ++i)
            #pragma unroll
            for (int j = 0; j < 2; ++j)
                acc[i][jh*2+j] = __builtin_amdgcn_mfma_i32_16x16x64_i8(
                    af[i], bf[jh*2+j], acc[i][jh*2+j], 0, 0, 0);
        __builtin_amdgcn_s_setprio(0);
    };

    // prologue: tiles 0 and 1 in flight (3 glds ops each, per wave)
    gldsA(0, 0); gldsB(0, 0, 0); gldsB(0, 0, 1);
    gldsA(1, 1); gldsB(1, 1, 0); gldsB(1, 1, 1);

    #pragma unroll
    for (int t = 0; t < 16; ++t) {
        const int buf = t % 3;
        // queue (per wave): [t's 3 (oldest), t+1's 3] -> retire exactly t's
        if (t < 15) WAITV3(); else WAITV0();
        BAR();                               // all waves' glds(t) visible
        // issue t+2 into buf (t+2)%3: WAR-safe (post-BAR, all waves are past
        // tile t-1 reads; (t+2)%3 differs from t%3 and (t+1)%3)
        if (t + 2 < 16) {
            const int nb = (t + 2) % 3;
            gldsA(t + 2, nb); gldsB(t + 2, nb, 0); gldsB(t + 2, nb, 1);
        }
        // ---- P0: A + B-half0 reads; MFMA j=0,1 ----
        readA(buf); readBh(buf, 0);
        BAR();
        mfma8(0);
        BAR();
        // ---- P1: B-half1 reads; MFMA j=2,3 ----
        readBh(buf, 1);
        BAR();
        mfma8(1);
    }

    // epilogue: (acc_i32 + rint(b/s_x)) * (s_w*s_x); exact (|acc|+|b32| < 2^24)
    // C/D layout: col = lane&15, row = (lane>>4)*4 + r
    const int bm0 = bm_idx * 128, bn0 = bn_idx * 256;
    #pragma unroll
    for (int n = 0; n < 4; ++n) {
        const int col = bn0 + wn + n * 16 + fr;
        const float sa  = SW[col] * sx;
        const float b32 = rintf(Bq[col] * inv_sx);
        #pragma unroll
        for (int m = 0; m < 4; ++m) {
            const size_t r0 = (size_t)(bm0 + wm + m * 16 + fg * 4) * N_TOTAL + col;
            #pragma unroll
            for (int r = 0; r < 4; ++r)
                Out[r0 + (size_t)r * N_TOTAL] = ((float)acc[m][n][r] + b32) * sa;
        }
    }
}

// ===================== FALLBACK (r5 bf16 kernel, 221us) ======================
__global__ void wconv_bf(const float* __restrict__ Wq, ushort* __restrict__ Wb) {
    const int n = blockIdx.x, c4 = threadIdx.x * 4;
    float4 v = *(const float4*)(Wq + (size_t)n * K_TOTAL + c4);
    const int bnb = n >> 8, row = n & 255, kt = c4 >> 6, c = c4 & 63;
    const int cs = c ^ ((row & 7) << 3);
    ushort* dst = Wb + ((size_t)(bnb * 16 + kt) * 16384 + row * 64 + cs);
    *(uint2*)dst = make_uint2(pkhi(v.x, v.y), pkhi(v.z, v.w));
}

__global__ __launch_bounds__(512, 2)
void qgemm_bf(const float* __restrict__ X, const float* __restrict__ SXp,
              const ushort* __restrict__ Wb, const float* __restrict__ SW,
              const float* __restrict__ Bq, float* __restrict__ Out)
{
    __shared__ uint4 smem4[8192];
    char* const smem = (char*)smem4;
    const int tid = threadIdx.x;
    const int d = blockIdx.x;
    const int g = (d & 7) * 128 + (d >> 3);
    const int bn_idx = g & 3, bm_idx = g >> 2;
    const int bm0 = bm_idx * 256, bn0 = bn_idx * 256;
    const float sx = SXp[0], inv_sx = 1.0f / sx;
    const int ar = tid >> 2, ac = (tid & 3) << 4;
    const float* xg = X + (size_t)(bm0 + ar) * K_TOTAL + ac;
    const int awslot = (tid & 3) << 1;
    const int awsw0 = ((awslot    ) ^ (ar & 7)) << 4;
    const int awsw1 = ((awslot + 1) ^ (ar & 7)) << 4;
    const int lane = tid & 63, w = tid >> 6;
    const int wm = (w >> 2) << 7, wn = (w & 3) << 6;
    const int fr = lane & 15, fg = lane >> 4;
    const int s0 = ((fg    ) ^ (fr & 7)) << 4;
    const int s1 = ((fg + 4) ^ (fr & 7)) << 4;
    const int arow = (wm + fr) * 128, brow = (wn + fr) * 128;
    const char* wsrc = (const char*)Wb + (size_t)bn_idx * 16 * 32768
                     + w * 4096 + lane * 16;
    f32x4 acc[8][4] = {};
    float4 xh0[4], xh1[4];
    short8 af[4], bf[4];
    auto issueA = [&](int kt, int h, float4* dst) {
        const float4* p = (const float4*)(xg + (size_t)h * 128 * K_TOTAL + kt * 64);
        dst[0] = p[0]; dst[1] = p[1]; dst[2] = p[2]; dst[3] = p[3];
    };
    auto packA = [&](int buf, int h, const float4* v) {
        unsigned u[8];
        #pragma unroll
        for (int q = 0; q < 4; ++q) {
            u[2*q+0] = pkhi(rintf(v[q].x * inv_sx), rintf(v[q].y * inv_sx));
            u[2*q+1] = pkhi(rintf(v[q].z * inv_sx), rintf(v[q].w * inv_sx));
        }
        char* base = smem + buf * 32768 + (h * 128 + ar) * 128;
        *(uint4*)(base + awsw0) = make_uint4(u[0], u[1], u[2], u[3]);
        *(uint4*)(base + awsw1) = make_uint4(u[4], u[5], u[6], u[7]);
    };
    auto gldsB = [&](int kt, int buf) {
        const char* src = wsrc + (size_t)kt * 32768;
        char* dst = smem + 65536 + buf * 32768 + w * 4096;
        __builtin_amdgcn_global_load_lds((glb_vp*)(src +    0), (lds_vp*)(dst +    0), 16, 0, 0);
        __builtin_amdgcn_global_load_lds((glb_vp*)(src + 1024), (lds_vp*)(dst + 1024), 16, 0, 0);
        __builtin_amdgcn_global_load_lds((glb_vp*)(src + 2048), (lds_vp*)(dst + 2048), 16, 0, 0);
        __builtin_amdgcn_global_load_lds((glb_vp*)(src + 3072), (lds_vp*)(dst + 3072), 16, 0, 0);
    };
    auto readA = [&](int buf, int mh, int sk) {
        const char* base = smem + buf * 32768 + arow;
        #pragma unroll
        for (int i = 0; i < 4; ++i)
            af[i] = *(const short8*)(base + (mh * 64 + i * 16) * 128 + sk);
    };
    auto readB = [&](int buf, int sk) {
        const char* base = smem + 65536 + buf * 32768 + brow;
        #pragma unroll
        for (int j = 0; j < 4; ++j)
            bf[j] = *(const short8*)(base + (j * 16) * 128 + sk);
    };
    auto mfma16 = [&](int mh) {
        __builtin_amdgcn_s_setprio(1);
        #pragma unroll
        for (int i = 0; i < 4; ++i)
            #pragma unroll
            for (int j = 0; j < 4; ++j)
                acc[mh*4+i][j] = __builtin_amdgcn_mfma_f32_16x16x32_bf16(
                    af[i], bf[j], acc[mh*4+i][j], 0, 0, 0);
        __builtin_amdgcn_s_setprio(0);
    };
    issueA(0, 0, xh0); issueA(0, 1, xh1);
    gldsB(0, 0);
    packA(0, 0, xh0); packA(0, 1, xh1);
    issueA(1, 0, xh0); issueA(1, 1, xh1);
    WAITV8(); WAITL0(); BAR();
    for (int t = 0; t < 16; ++t) {
        const int cur = t & 1, nxt = cur ^ 1;
        const bool pf  = (t + 1 < 16);
        const bool pf2 = (t + 2 < 16);
        if (pf) gldsB(t + 1, nxt);
        readA(cur, 0, s0); readB(cur, s0);
        BAR(); mfma16(0); BAR();
        readA(cur, 1, s0);
        BAR(); mfma16(1); BAR();
        if (pf)  packA(nxt, 0, xh0);
        if (pf2) issueA(t + 2, 0, xh0);
        readA(cur, 0, s1); readB(cur, s1);
        BAR(); mfma16(0); BAR();
        if (pf)  packA(nxt, 1, xh1);
        if (pf2) issueA(t + 2, 1, xh1);
        readA(cur, 1, s1);
        BAR(); mfma16(1);
        if (pf) {
            if (pf2) WAITV8(); else WAITV0();
            WAITL0(); BAR();
        }
    }
    #pragma unroll
    for (int n = 0; n < 4; ++n) {
        const int col = bn0 + wn + n * 16 + fr;
        const float sa  = SW[col] * sx;
        const float b32 = rintf(Bq[col] * inv_sx);
        #pragma unroll
        for (int m = 0; m < 8; ++m) {
            const size_t r0 = (size_t)(bm0 + wm + m * 16 + fg * 4) * N_TOTAL + col;
            #pragma unroll
            for (int r = 0; r < 4; ++r)
                Out[r0 + (size_t)r * N_TOTAL] = (acc[m][n][r] + b32) * sa;
        }
    }
}

__global__ void sa_tail(const float* __restrict__ SW, const float* __restrict__ SXp,
                        float* __restrict__ Out)
{
    int o = blockIdx.x * blockDim.x + threadIdx.x;
    if (o < N_TOTAL) Out[(size_t)M_TOTAL * N_TOTAL + o] = SW[o] * SXp[0];
}

extern "C" void kernel_launch(void* const* d_in, const int* in_sizes, int n_in,
                              void* d_out, int out_size, void* d_ws, size_t ws_size,
                              hipStream_t stream)
{
    const float* x  = (const float*)d_in[0];
    const float* sx = (const float*)d_in[1];
    const float* wq = (const float*)d_in[2];
    const float* sw = (const float*)d_in[3];
    const float* bq = (const float*)d_in[4];
    float* out = (float*)d_out;

    const size_t W_BYTES = 1u << 20;          // Wb: 1 MiB
    const size_t X_BYTES = (size_t)64 << 20;  // Xb: 64 MiB

    if (ws_size >= W_BYTES + X_BYTES) {
        char* wbuf = (char*)d_ws;
        char* xbuf = (char*)d_ws + W_BYTES;
        wconv8<<<1024, 256, 0, stream>>>(wq, sx, sw, wbuf, out);
        xconv8<<<16384, 256, 0, stream>>>(x, sx, xbuf);
        qgemm8<<<2048, 512, 0, stream>>>(xbuf, sx, wbuf, sw, bq, out);
    } else {
        ushort* wbuf = (ushort*)d_ws;         // 2 MiB (r5 path)
        wconv_bf<<<1024, 256, 0, stream>>>(wq, wbuf);
        qgemm_bf<<<1024, 512, 0, stream>>>(x, sx, wbuf, sw, bq, out);
        sa_tail<<<4, 256, 0, stream>>>(sw, sx, out);
    }
}